// Round 5
// baseline (22086.931 us; speedup 1.0000x reference)
//
#include <hip/hip_runtime.h>

#define B_ 128
#define T_ 2048

typedef float vf32 __attribute__((ext_vector_type(32)));

__device__ __forceinline__ float fast_sigmoid(float x){
    return 1.0f / (1.0f + __expf(-x));
}
__device__ __forceinline__ float fast_tanh(float x){
    float a = fabsf(x);
    float e = __expf(2.0f*a);
    float r = 1.0f - 2.0f/(e + 1.0f);   // e=inf -> r=1, no NaN
    return (x < 0.0f) ? -r : r;
}

// ---------------------------------------------------------------------------
// Scan kernel: one workgroup per batch element b.  TWO barriers per timestep
// (was four -- R0..R4 proved the kernel is bound by the serial barrier/LDS
// latency structure, not by VALU or registers: VALUBusy rose 10->17% across
// rounds while dur stayed at ~3.4ms = 2049 iters x 4 x ~0.4us segments).
//
// Wave roles (512 threads):
//   waves 0-3 (tid<256) : LSTM gate matvec in S1 (gate g = tid)
//   wave 0   (tid<64)   : LSTM activations + h write in S2
//   wave 5              : trans SA in S1: matvec1 (2 rows/lane, 138 w),
//                         in-wave LN reduce via shfl_xor (no LDS round-trip),
//                         tanh, h1 write.  One wave owns the whole phase.
//   wave 4              : trans SB in S2: matvec2 (full w2 row = 128 w/lane),
//                         h2, matvec3 via shuffles, z + output writes.
//   wave 6 (lanes 0-31) : obs prefetch (global->reg->LDS) in S2
//
// Register-layout invariant (R3 lesson): ALL roles store weights in the SAME
// five 32-wide SSA vectors W0..W4 (union storage, 160 slots), constant
// subscripts only.  Live set ~160 + temps -> ~200 VGPRs, under the 256 cap
// at 2 waves/SIMD (grid = 128 blocks on 256 CUs -> 1 block/CU regardless).
//   LSTM:   W0=Wih row, W1=Whh[0..31], W2=Whh[32..63]
//   wave 5: W0,W1=t_w1[row0][0..63], W3,W4=t_w1[row1][0..63],
//           W2[0..4]=row0[64..68], W2[5..9]=row1[64..68]
//   wave 4: W0..W3 = t_w2 row (128), W4[0..15] = t_w3 sixteenth
// ---------------------------------------------------------------------------
__global__ __launch_bounds__(512)
__attribute__((amdgpu_waves_per_eu(2, 2)))
void scan_kernel(
    const float* __restrict__ obs,
    const float* __restrict__ Wih,
    const float* __restrict__ Whh,
    const float* __restrict__ bih,
    const float* __restrict__ bhh,
    const float* __restrict__ tw1,
    const float* __restrict__ tb1,
    const float* __restrict__ tg,
    const float* __restrict__ tbeta,
    const float* __restrict__ tw2,
    const float* __restrict__ tb2,
    const float* __restrict__ tw3,
    const float* __restrict__ tb3,
    const float* __restrict__ z0m,
    const float* __restrict__ z0lv,
    float* __restrict__ out_tm,
    float* __restrict__ out_tlv)
{
    __shared__ __align__(16) float comb_s[2][72];   // [0..63]=h, [64..68]=z, [69..71]=0 pad
    __shared__ __align__(16) float obs_s[2][32];
    __shared__ float gates_s[256];
    __shared__ __align__(16) float h1_s[128];

    const int tid  = threadIdx.x;
    const int wid  = tid >> 6;
    const int lane = tid & 63;
    const int b    = blockIdx.x;

    vf32 W0, W1, W2, W3, W4;
    #pragma unroll
    for (int k = 0; k < 32; k++) { W0[k]=0.f; W1[k]=0.f; W2[k]=0.f; W3[k]=0.f; W4[k]=0.f; }

    float biasg = 0.f;
    float b1r0 = 0.f, b1r1 = 0.f, gr0 = 0.f, gr1 = 0.f, ber0 = 0.f, ber1 = 0.f;
    float b2r = 0.f, b3r = 0.f;
    float c_st = 0.f;
    float ld_carry = 0.f;

    if (wid < 4) {                      // LSTM: gate g = tid
        biasg = bih[tid] + bhh[tid];
        #pragma unroll
        for (int k = 0; k < 32; k++) W0[k] = Wih[tid*32 + k];
        #pragma unroll
        for (int k = 0; k < 32; k++) W1[k] = Whh[tid*64 + k];
        #pragma unroll
        for (int k = 0; k < 32; k++) W2[k] = Whh[tid*64 + 32 + k];
    } else if (wid == 5) {              // trans SA: rows r0=lane, r1=64+lane
        const int r0 = lane, r1 = 64 + lane;
        #pragma unroll
        for (int k = 0; k < 32; k++) W0[k] = tw1[r0*69 + k];
        #pragma unroll
        for (int k = 0; k < 32; k++) W1[k] = tw1[r0*69 + 32 + k];
        #pragma unroll
        for (int k = 0; k < 32; k++) W3[k] = tw1[r1*69 + k];
        #pragma unroll
        for (int k = 0; k < 32; k++) W4[k] = tw1[r1*69 + 32 + k];
        #pragma unroll
        for (int k = 0; k < 5;  k++) { W2[k] = tw1[r0*69 + 64 + k]; W2[5+k] = tw1[r1*69 + 64 + k]; }
        b1r0 = tb1[r0]; b1r1 = tb1[r1];
        gr0  = tg[r0];  gr1  = tg[r1];
        ber0 = tbeta[r0]; ber1 = tbeta[r1];
    } else if (wid == 4) {              // trans SB: h2 output j = lane
        #pragma unroll
        for (int k = 0; k < 32; k++) W0[k] = tw2[lane*128 + k];
        #pragma unroll
        for (int k = 0; k < 32; k++) W1[k] = tw2[lane*128 + 32 + k];
        #pragma unroll
        for (int k = 0; k < 32; k++) W2[k] = tw2[lane*128 + 64 + k];
        #pragma unroll
        for (int k = 0; k < 32; k++) W3[k] = tw2[lane*128 + 96 + k];
        b2r = tb2[lane];
        if (lane < 40) {
            const int j = lane >> 2, pp = lane & 3;
            #pragma unroll
            for (int k = 0; k < 16; k++) W4[k] = tw3[j*64 + pp*16 + k];
            b3r = tb3[j];
        }
    }

    // LDS / output init
    if (tid < 64) comb_s[1][tid] = 0.f;           // h_{-1} = 0 (read at i=0)
    if (tid < 5) {
        comb_s[1][64 + tid] = z0m[tid];           // z for first trans step (t=1)
        out_tm [(size_t)b*T_*5 + tid] = z0m[tid];   // trans_means[t=0]  = z0_mean
        out_tlv[(size_t)b*T_*5 + tid] = z0lv[tid];  // trans_logvars[0]  = z0_log_var
    }
    if (tid < 3) { comb_s[0][69 + tid] = 0.f; comb_s[1][69 + tid] = 0.f; }
    if (tid >= 64 && tid < 69) comb_s[0][tid] = 0.f;   // z slot of buf 0 (defensive init)
    if (wid == 6 && lane < 32) {
        obs_s[0][lane] = obs[(size_t)b*T_*32 + lane];       // t=0
        ld_carry       = obs[((size_t)b*T_ + 1)*32 + lane]; // t=1 in flight
    }
    __syncthreads();

    for (int i = 0; i <= T_; ++i) {
        const int cur = i & 1, prev = cur ^ 1;
        const bool lstm_on  = (i < T_);
        const bool trans_on = (i >= 2);   // processes t_tr = i-1 in [1, T-1]

        // ================= S1: LSTM gate matvec || trans SA =================
        if (wid < 4) {
            if (lstm_on) {
                float acc0 = biasg, acc1 = 0.f, acc2 = 0.f, acc3 = 0.f;
                const float4* ob4 = (const float4*)obs_s[cur];
                #pragma unroll
                for (int k4 = 0; k4 < 8; k4++) {
                    float4 o = ob4[k4];
                    acc0 += W0[k4*4+0]*o.x;
                    acc1 += W0[k4*4+1]*o.y;
                    acc2 += W0[k4*4+2]*o.z;
                    acc3 += W0[k4*4+3]*o.w;
                }
                const float4* hb4 = (const float4*)comb_s[prev];
                #pragma unroll
                for (int k4 = 0; k4 < 8; k4++) {
                    float4 h = hb4[k4];
                    acc0 += W1[k4*4+0]*h.x;
                    acc1 += W1[k4*4+1]*h.y;
                    acc2 += W1[k4*4+2]*h.z;
                    acc3 += W1[k4*4+3]*h.w;
                }
                #pragma unroll
                for (int k4 = 0; k4 < 8; k4++) {
                    float4 h = hb4[8 + k4];
                    acc0 += W2[k4*4+0]*h.x;
                    acc1 += W2[k4*4+1]*h.y;
                    acc2 += W2[k4*4+2]*h.z;
                    acc3 += W2[k4*4+3]*h.w;
                }
                gates_s[tid] = (acc0 + acc1) + (acc2 + acc3);
            }
        } else if (wid == 5) {
            if (trans_on) {
                // matvec1: 2 rows per lane over comb[prev][0..68]
                float a0 = b1r0, a0b = 0.f, a1 = b1r1, a1b = 0.f;
                const float4* cb4 = (const float4*)comb_s[prev];
                #pragma unroll
                for (int k4 = 0; k4 < 8; k4++) {
                    float4 cv = cb4[k4];
                    a0  += W0[k4*4+0]*cv.x + W0[k4*4+2]*cv.z;
                    a0b += W0[k4*4+1]*cv.y + W0[k4*4+3]*cv.w;
                    a1  += W3[k4*4+0]*cv.x + W3[k4*4+2]*cv.z;
                    a1b += W3[k4*4+1]*cv.y + W3[k4*4+3]*cv.w;
                }
                #pragma unroll
                for (int k4 = 0; k4 < 8; k4++) {
                    float4 cv = cb4[8 + k4];
                    a0  += W1[k4*4+0]*cv.x + W1[k4*4+2]*cv.z;
                    a0b += W1[k4*4+1]*cv.y + W1[k4*4+3]*cv.w;
                    a1  += W4[k4*4+0]*cv.x + W4[k4*4+2]*cv.z;
                    a1b += W4[k4*4+1]*cv.y + W4[k4*4+3]*cv.w;
                }
                {   // k = 64..67
                    float4 cv = cb4[16];
                    a0  += W2[0]*cv.x + W2[2]*cv.z;
                    a0b += W2[1]*cv.y + W2[3]*cv.w;
                    a1  += W2[5]*cv.x + W2[7]*cv.z;
                    a1b += W2[6]*cv.y + W2[8]*cv.w;
                }
                {   // k = 68
                    float c68 = comb_s[prev][68];
                    a0 += W2[4]*c68;
                    a1 += W2[9]*c68;
                }
                a0 += a0b; a1 += a1b;
                // in-wave LN reduce over all 128 rows (2 per lane)
                float s1 = a0 + a1, s2 = a0*a0 + a1*a1;
                #pragma unroll
                for (int m = 1; m < 64; m <<= 1) {
                    s1 += __shfl_xor(s1, m, 64);
                    s2 += __shfl_xor(s2, m, 64);
                }
                const float mean = s1 * (1.0f/128.0f);
                const float var  = fmaxf(s2 * (1.0f/128.0f) - mean*mean, 0.0f);
                const float rs   = rsqrtf(var + 1e-5f);
                h1_s[lane]      = fast_tanh((a0 - mean)*rs*gr0 + ber0);
                h1_s[64 + lane] = fast_tanh((a1 - mean)*rs*gr1 + ber1);
            }
        }
        __syncthreads();

        // ====== S2: LSTM activations || trans SB || obs prefetch ======
        if (tid < 64) {
            if (lstm_on) {
                float iv = fast_sigmoid(gates_s[tid]);
                float fv = fast_sigmoid(gates_s[64 + tid]);
                float gv = fast_tanh   (gates_s[128 + tid]);
                float ov = fast_sigmoid(gates_s[192 + tid]);
                c_st = fv*c_st + iv*gv;
                comb_s[cur][tid] = ov * fast_tanh(c_st);
            }
        } else if (wid == 4) {
            if (trans_on) {
                // matvec2: h2[lane] = tanh(b2 + w2[lane][:] . h1[:])
                float acc0 = b2r, acc1 = 0.f, acc2 = 0.f, acc3 = 0.f;
                const float4* h14 = (const float4*)h1_s;
                #pragma unroll
                for (int k4 = 0; k4 < 8; k4++) {
                    float4 h = h14[k4];
                    acc0 += W0[k4*4+0]*h.x;
                    acc1 += W0[k4*4+1]*h.y;
                    acc2 += W0[k4*4+2]*h.z;
                    acc3 += W0[k4*4+3]*h.w;
                }
                #pragma unroll
                for (int k4 = 0; k4 < 8; k4++) {
                    float4 h = h14[8 + k4];
                    acc0 += W1[k4*4+0]*h.x;
                    acc1 += W1[k4*4+1]*h.y;
                    acc2 += W1[k4*4+2]*h.z;
                    acc3 += W1[k4*4+3]*h.w;
                }
                #pragma unroll
                for (int k4 = 0; k4 < 8; k4++) {
                    float4 h = h14[16 + k4];
                    acc0 += W2[k4*4+0]*h.x;
                    acc1 += W2[k4*4+1]*h.y;
                    acc2 += W2[k4*4+2]*h.z;
                    acc3 += W2[k4*4+3]*h.w;
                }
                #pragma unroll
                for (int k4 = 0; k4 < 8; k4++) {
                    float4 h = h14[24 + k4];
                    acc0 += W3[k4*4+0]*h.x;
                    acc1 += W3[k4*4+1]*h.y;
                    acc2 += W3[k4*4+2]*h.z;
                    acc3 += W3[k4*4+3]*h.w;
                }
                float h2v = fast_tanh((acc0 + acc1) + (acc2 + acc3));
                // matvec3 via shuffles: lane (4j+pp) accumulates row j over
                // input chunk pp*16..pp*16+15
                const int pp = lane & 3;
                float acc = 0.f;
                #pragma unroll
                for (int k = 0; k < 16; k++)
                    acc += W4[k] * __shfl(h2v, pp*16 + k, 64);
                acc += __shfl_xor(acc, 1, 64);
                acc += __shfl_xor(acc, 2, 64);   // lanes 4j..4j+3 hold row-j total
                if (pp == 0 && lane < 40) {
                    const int j = lane >> 2;     // 0..9
                    float val = b3r + acc;
                    const int t_tr = i - 1;
                    const size_t row = (size_t)b*T_ + t_tr;
                    if (j < 5) {
                        comb_s[cur][64 + j] = val;                  // z feedback
                        out_tm[row*5 + j] = val;
                    } else {
                        out_tlv[row*5 + (j - 5)] = fminf(10.0f, fmaxf(-10.0f, val));
                    }
                }
            }
        } else if (wid == 6 && lane < 32) {
            const int t_w = i + 1, t_l = i + 2;
            if (t_w < T_) obs_s[t_w & 1][lane] = ld_carry;
            if (t_l < T_) ld_carry = obs[((size_t)b*T_ + t_l)*32 + lane];
        }
        __syncthreads();
    }
}

// ---------------------------------------------------------------------------
// Observation decoder: one wave per row; weights in static LDS (~60 KB);
// h1/h2 are staged once per row into a per-wave LDS strip and re-read as
// BROADCAST float4 loads (same address across lanes = conflict-free, one DS
// op per 4 values). Accumulators split 4-way to break the serial FMA chain.
// ---------------------------------------------------------------------------
#define DEC_BLOCKS 512

__global__ __launch_bounds__(512) void dec_kernel(
    const float* __restrict__ ow1,
    const float* __restrict__ ob1,
    const float* __restrict__ og,
    const float* __restrict__ obeta,
    const float* __restrict__ ow2,
    const float* __restrict__ ob2,
    const float* __restrict__ ow3,
    const float* __restrict__ ob3,
    const float* __restrict__ tmeans,
    float* __restrict__ out_om,
    float* __restrict__ out_olv)
{
    __shared__ float w1s[640];    // [j*5+k]
    __shared__ float b1s[128], gs[128], bes[128];
    __shared__ float w2s[8192];   // [k*64+j] transposed
    __shared__ float b2s[64];
    __shared__ float w3s[4096];   // [k*64+j] transposed
    __shared__ float b3s[64];
    __shared__ __align__(16) float h1s[8][128];   // per-wave h1 strip
    __shared__ __align__(16) float h2s[8][64];    // per-wave h2 strip

    const int tid = threadIdx.x;
    for (int idx = tid; idx < 640; idx += 512) w1s[idx] = ow1[idx];
    for (int idx = tid; idx < 128; idx += 512) {
        b1s[idx] = ob1[idx]; gs[idx] = og[idx]; bes[idx] = obeta[idx];
    }
    for (int idx = tid; idx < 8192; idx += 512) {
        int k = idx >> 6, j = idx & 63;
        w2s[idx] = ow2[j*128 + k];
    }
    for (int idx = tid; idx < 4096; idx += 512) {
        int k = idx >> 6, j = idx & 63;
        w3s[idx] = ow3[j*64 + k];
    }
    for (int idx = tid; idx < 64; idx += 512) { b2s[idx] = ob2[idx]; b3s[idx] = ob3[idx]; }
    __syncthreads();

    const int lane   = tid & 63;
    const int wv     = tid >> 6;
    const int gwave  = (blockIdx.x * 512 + tid) >> 6;
    const int nwaves = DEC_BLOCKS * 8;
    const int j0 = lane, j1 = lane + 64;

    for (int row = gwave; row < B_*T_; row += nwaves) {
        const float z0v = tmeans[(size_t)row*5 + 0];
        const float z1v = tmeans[(size_t)row*5 + 1];
        const float z2v = tmeans[(size_t)row*5 + 2];
        const float z3v = tmeans[(size_t)row*5 + 3];
        const float z4v = tmeans[(size_t)row*5 + 4];

        // layer 1 (5 -> 128): lane holds outputs j0 and j1
        float a = b1s[j0] + w1s[j0*5+0]*z0v + w1s[j0*5+1]*z1v + w1s[j0*5+2]*z2v
                + w1s[j0*5+3]*z3v + w1s[j0*5+4]*z4v;
        float bb = b1s[j1] + w1s[j1*5+0]*z0v + w1s[j1*5+1]*z1v + w1s[j1*5+2]*z2v
                 + w1s[j1*5+3]*z3v + w1s[j1*5+4]*z4v;
        float s1 = a + bb, s2 = a*a + bb*bb;
        #pragma unroll
        for (int m = 1; m < 64; m <<= 1) {
            s1 += __shfl_xor(s1, m, 64);
            s2 += __shfl_xor(s2, m, 64);
        }
        const float mean = s1 * (1.0f/128.0f);
        const float var  = fmaxf(s2 * (1.0f/128.0f) - mean*mean, 0.0f);
        const float rs   = rsqrtf(var + 1e-5f);
        const float h1a  = fast_tanh((a  - mean)*rs*gs[j0] + bes[j0]);
        const float h1b  = fast_tanh((bb - mean)*rs*gs[j1] + bes[j1]);

        // stage h1 into the wave's private LDS strip (wave-synchronous)
        h1s[wv][lane]      = h1a;
        h1s[wv][64 + lane] = h1b;
        __builtin_amdgcn_wave_barrier();

        // layer 2 (128 -> 64): lane computes output j = lane.
        float acc2a = b2s[lane], acc2b = 0.f, acc2c = 0.f, acc2d = 0.f;
        const float4* h14 = (const float4*)(h1s[wv]);
        #pragma unroll
        for (int k4 = 0; k4 < 32; k4++) {
            float4 h = h14[k4];
            acc2a += h.x * w2s[(k4*4+0)*64 + lane];
            acc2b += h.y * w2s[(k4*4+1)*64 + lane];
            acc2c += h.z * w2s[(k4*4+2)*64 + lane];
            acc2d += h.w * w2s[(k4*4+3)*64 + lane];
        }
        const float h2v = fast_tanh(acc2a + acc2b + acc2c + acc2d);

        h2s[wv][lane] = h2v;
        __builtin_amdgcn_wave_barrier();

        // layer 3 (64 -> 64): lane computes output j = lane
        float acc3a = b3s[lane], acc3b = 0.f, acc3c = 0.f, acc3d = 0.f;
        const float4* h24 = (const float4*)(h2s[wv]);
        #pragma unroll
        for (int k4 = 0; k4 < 16; k4++) {
            float4 h = h24[k4];
            acc3a += h.x * w3s[(k4*4+0)*64 + lane];
            acc3b += h.y * w3s[(k4*4+1)*64 + lane];
            acc3c += h.z * w3s[(k4*4+2)*64 + lane];
            acc3d += h.w * w3s[(k4*4+3)*64 + lane];
        }
        const float acc3 = acc3a + acc3b + acc3c + acc3d;

        if (lane < 32) {
            out_om[(size_t)row*32 + lane] = acc3;
        } else {
            out_olv[(size_t)row*32 + (lane - 32)] = fminf(10.0f, fmaxf(-10.0f, acc3));
        }
    }
}

extern "C" void kernel_launch(void* const* d_in, const int* in_sizes, int n_in,
                              void* d_out, int out_size, void* d_ws, size_t ws_size,
                              hipStream_t stream) {
    const float* obs  = (const float*)d_in[0];
    const float* Wih  = (const float*)d_in[1];
    const float* Whh  = (const float*)d_in[2];
    const float* bih  = (const float*)d_in[3];
    const float* bhh  = (const float*)d_in[4];
    const float* tw1  = (const float*)d_in[5];
    const float* tb1  = (const float*)d_in[6];
    const float* tg   = (const float*)d_in[7];
    const float* tbe  = (const float*)d_in[8];
    const float* tw2  = (const float*)d_in[9];
    const float* tb2  = (const float*)d_in[10];
    const float* tw3  = (const float*)d_in[11];
    const float* tb3  = (const float*)d_in[12];
    const float* ow1  = (const float*)d_in[13];
    const float* ob1  = (const float*)d_in[14];
    const float* og   = (const float*)d_in[15];
    const float* obe  = (const float*)d_in[16];
    const float* ow2  = (const float*)d_in[17];
    const float* ob2  = (const float*)d_in[18];
    const float* ow3  = (const float*)d_in[19];
    const float* ob3  = (const float*)d_in[20];
    const float* z0m  = (const float*)d_in[21];
    const float* z0lv = (const float*)d_in[22];

    float* out0 = (float*)d_out;                   // obs_means   (B,T,32)
    float* out1 = out0 + (size_t)B_*T_*32;         // obs_logvars (B,T,32)
    float* out2 = out1 + (size_t)B_*T_*32;         // trans_means (B,T,5)
    float* out3 = out2 + (size_t)B_*T_*5;          // trans_logvars

    scan_kernel<<<B_, 512, 0, stream>>>(obs, Wih, Whh, bih, bhh,
                                        tw1, tb1, tg, tbe, tw2, tb2, tw3, tb3,
                                        z0m, z0lv, out2, out3);

    dec_kernel<<<DEC_BLOCKS, 512, 0, stream>>>(
        ow1, ob1, og, obe, ow2, ob2, ow3, ob3, out2, out0, out1);
}

// Round 6
// 3817.903 us; speedup vs baseline: 5.7851x; 5.7851x over previous
//
#include <hip/hip_runtime.h>

#define B_ 128
#define T_ 2048

typedef float vf32 __attribute__((ext_vector_type(32)));

__device__ __forceinline__ float fast_sigmoid(float x){
    return 1.0f / (1.0f + __expf(-x));
}
__device__ __forceinline__ float fast_tanh(float x){
    float a = fabsf(x);
    float e = __expf(2.0f*a);
    float r = 1.0f - 2.0f/(e + 1.0f);   // e=inf -> r=1, no NaN
    return (x < 0.0f) ? -r : r;
}

// LDS flag sync helpers (workgroup scope, acquire/release)
__device__ __forceinline__ void wait_ge(int* p, int v){
    while (__hip_atomic_load(p, __ATOMIC_ACQUIRE, __HIP_MEMORY_SCOPE_WORKGROUP) < v) { }
}
__device__ __forceinline__ void st_rel(int* p, int v){
    __hip_atomic_store(p, v, __ATOMIC_RELEASE, __HIP_MEMORY_SCOPE_WORKGROUP);
}

// ---------------------------------------------------------------------------
// Scan kernel: one workgroup per batch element b.  NO in-loop __syncthreads.
// R0-R5 established: (a) VGPR budget is effectively ~96 weights/lane (alloc
// caps at ~128 total; exceeding it spills catastrophically -- R5); (b) the
// kernel is bound by the serial 4-barrier lockstep (R0 spilled vs R4 clean:
// identical 3.4ms).  So: decouple the two recurrences into asynchronous wave
// groups synced by LDS acquire/release flags.
//
//   LSTM group (waves 0-3): gate g = tid, 96 w/lane.  Each step: matvec ->
//     gates_s -> gflag[w] -> wave0 does activations, writes h into hring
//     (8-deep), publishes lstm_t.  Wave1 also streams obs into oring.
//   Trans group (waves 4-7): step t (1..T-1) uses h(t) from hring + z(t-1).
//     mv1: 2 lanes/row (37 w) -> pair shfl + 64-lane butterfly -> lnp ->
//     tfA 4-wave sync -> LN+tanh -> h1loc (wave-local; mv2's K-split range
//     == own wave's rows, so NO cross-wave sync) -> mv2 (32 w) -> tfB ->
//     wave4 combines, h2, mv3 (16 w, shfl gather), writes z + outputs,
//     publishes ttag.
//   Back-pressure: LSTM wave0 waits ttag >= t-8 before overwriting hring.
//   Dependency graph is acyclic (LSTM ahead, trans behind; no mutual wait).
//
// Union storage (R3 lesson): every role keeps weights in the SAME V0,V1,V2
// (96 slots) with constant subscripts; max live = 96 + scalars, matching the
// proven-clean R4 allocation (124 VGPR, zero in-loop spill).
// ---------------------------------------------------------------------------
__global__ __launch_bounds__(512)
__attribute__((amdgpu_waves_per_eu(2, 2)))
void scan_kernel(
    const float* __restrict__ obs,
    const float* __restrict__ Wih,
    const float* __restrict__ Whh,
    const float* __restrict__ bih,
    const float* __restrict__ bhh,
    const float* __restrict__ tw1,
    const float* __restrict__ tb1,
    const float* __restrict__ tg,
    const float* __restrict__ tbeta,
    const float* __restrict__ tw2,
    const float* __restrict__ tb2,
    const float* __restrict__ tw3,
    const float* __restrict__ tb3,
    const float* __restrict__ z0m,
    const float* __restrict__ z0lv,
    float* __restrict__ out_tm,
    float* __restrict__ out_tlv)
{
    __shared__ __align__(16) float hring[8][64];   // LSTM h ring buffer
    __shared__ __align__(16) float oring[8][32];   // obs ring buffer
    __shared__ float gates_s[256];
    __shared__ __align__(16) float h1loc[4][32];   // per-trans-wave h1 slice
    __shared__ float p2s[4][64];                   // mv2 partials (1..3 used)
    __shared__ float lnp[8];
    __shared__ float z_s[8];                       // 5 used
    __shared__ int lstm_t_s;                       // last completed LSTM step
    __shared__ int ttag_s;                         // last completed trans step
    __shared__ int gflag[4];
    __shared__ int tfA[4];
    __shared__ int tfB[4];

    const int tid  = threadIdx.x;
    const int wid  = tid >> 6;
    const int lane = tid & 63;
    const int b    = blockIdx.x;

    vf32 V0, V1, V2;
    #pragma unroll
    for (int k = 0; k < 32; k++) { V0[k]=0.f; V1[k]=0.f; V2[k]=0.f; }

    float biasg = 0.f, b1r = 0.f, gr = 0.f, betar = 0.f, b2r = 0.f, b3r = 0.f;
    float c_st = 0.f;
    float carry = 0.f;

    if (wid < 4) {                       // LSTM: gate g = tid
        biasg = bih[tid] + bhh[tid];
        #pragma unroll
        for (int k = 0; k < 32; k++) V0[k] = Wih[tid*32 + k];
        #pragma unroll
        for (int k = 0; k < 32; k++) V1[k] = Whh[tid*64 + k];
        #pragma unroll
        for (int k = 0; k < 32; k++) V2[k] = Whh[tid*64 + 32 + k];
        if (wid == 1 && lane < 32)
            carry = obs[((size_t)b*T_ + 5)*32 + lane];    // obs(5) in flight
    } else {                             // trans
        const int q  = tid - 256;
        const int jr = q >> 1;           // mv1 row 0..127
        const int ph = q & 1;            // half of the 69-dot
        const int tw = wid - 4;          // trans wave 0..3
        #pragma unroll
        for (int k = 0; k < 32; k++) V0[k] = tw1[jr*69 + ph*32 + k];
        #pragma unroll
        for (int k = 0; k < 5;  k++) V2[k] = ph ? tw1[jr*69 + 64 + k] : 0.f;
        if (!ph) b1r = tb1[jr];
        gr = tg[jr]; betar = tbeta[jr];
        // mv2: output row = lane, K range = tw*32 .. tw*32+31 (== own rows)
        #pragma unroll
        for (int k = 0; k < 32; k++) V1[k] = tw2[lane*128 + tw*32 + k];
        if (tw == 0) {
            b2r = tb2[lane];
            if (lane < 40) {
                #pragma unroll
                for (int k = 0; k < 16; k++)
                    V2[5 + k] = tw3[(lane>>2)*64 + (lane&3)*16 + k];
                b3r = tb3[lane >> 2];
            }
        }
    }

    // LDS init
    if (tid < 64) hring[7][tid] = 0.f;            // h(-1) = 0
    if (tid < 160) oring[tid >> 5][tid & 31] =    // obs(0..4)
        obs[(size_t)b*T_*32 + tid];
    if (tid < 5) {
        z_s[tid] = z0m[tid];
        out_tm [(size_t)b*T_*5 + tid] = z0m[tid];   // trans_means[0]
        out_tlv[(size_t)b*T_*5 + tid] = z0lv[tid];  // trans_logvars[0]
    }
    if (tid == 0) { lstm_t_s = -1; ttag_s = 0; }
    if (tid < 4)  { gflag[tid] = -1; tfA[tid] = 0; tfB[tid] = 0; }
    __syncthreads();        // the ONLY workgroup barrier

    if (wid < 4) {
        // ======================= LSTM group =======================
        for (int t = 0; t < T_; ++t) {
            wait_ge(&lstm_t_s, t - 1);            // h(t-1) published
            const float4* ob4 = (const float4*)oring[t & 7];
            const float4* hb4 = (const float4*)hring[(t - 1) & 7];
            float a0 = biasg, a1 = 0.f, a2 = 0.f, a3 = 0.f;
            #pragma unroll
            for (int k4 = 0; k4 < 8; k4++) {
                float4 o = ob4[k4];
                a0 += V0[k4*4+0]*o.x;
                a1 += V0[k4*4+1]*o.y;
                a2 += V0[k4*4+2]*o.z;
                a3 += V0[k4*4+3]*o.w;
            }
            #pragma unroll
            for (int k4 = 0; k4 < 8; k4++) {
                float4 h = hb4[k4];
                a0 += V1[k4*4+0]*h.x;
                a1 += V1[k4*4+1]*h.y;
                a2 += V1[k4*4+2]*h.z;
                a3 += V1[k4*4+3]*h.w;
            }
            #pragma unroll
            for (int k4 = 0; k4 < 8; k4++) {
                float4 h = hb4[8 + k4];
                a0 += V2[k4*4+0]*h.x;
                a1 += V2[k4*4+1]*h.y;
                a2 += V2[k4*4+2]*h.z;
                a3 += V2[k4*4+3]*h.w;
            }
            gates_s[tid] = (a0 + a1) + (a2 + a3);

            if (wid == 1) {
                if (lane < 32 && t + 5 < T_)
                    oring[(t + 5) & 7][lane] = carry;   // obs(t+5) -> ring
                st_rel(&gflag[1], t);                   // covers obs write too
                if (lane < 32 && t + 6 < T_)
                    carry = obs[((size_t)b*T_ + t + 6)*32 + lane];
            } else if (wid >= 2) {
                st_rel(&gflag[wid], t);
            } else {
                // wave 0: activations + h publish
                wait_ge(&gflag[1], t);
                wait_ge(&gflag[2], t);
                wait_ge(&gflag[3], t);
                float iv = fast_sigmoid(gates_s[lane]);
                float fv = fast_sigmoid(gates_s[64 + lane]);
                float gv = fast_tanh   (gates_s[128 + lane]);
                float ov = fast_sigmoid(gates_s[192 + lane]);
                c_st = fv*c_st + iv*gv;
                float hv = ov * fast_tanh(c_st);
                wait_ge(&ttag_s, t - 8);            // ring back-pressure
                hring[t & 7][lane] = hv;
                st_rel(&lstm_t_s, t);
            }
        }
    } else {
        // ======================= trans group =======================
        const int tw = wid - 4;
        const int ph = tid & 1;
        for (int t = 1; t < T_; ++t) {
            wait_ge(&ttag_s, t - 1);               // z(t-1) ready
            wait_ge(&lstm_t_s, t);                 // h(t) ready
            // ---- mv1: 2 lanes/row over [h(t)(64) | z(5)] ----
            const float4* hb4 = (const float4*)hring[t & 7] + ph*8;
            float a0 = b1r, a1 = 0.f, a2 = 0.f, a3 = 0.f;
            #pragma unroll
            for (int k4 = 0; k4 < 8; k4++) {
                float4 h = hb4[k4];
                a0 += V0[k4*4+0]*h.x;
                a1 += V0[k4*4+1]*h.y;
                a2 += V0[k4*4+2]*h.z;
                a3 += V0[k4*4+3]*h.w;
            }
            float av = (a0 + a1) + (a2 + a3);
            av += V2[0]*z_s[0] + V2[1]*z_s[1] + V2[2]*z_s[2]
                + V2[3]*z_s[3] + V2[4]*z_s[4];     // ph0 lanes: V2[0..4]=0
            av += __shfl_xor(av, 1, 64);           // combine half-dots
            // ---- LN partial sums (each row counted twice -> /256) ----
            float s1 = av, s2 = av*av;
            #pragma unroll
            for (int m = 1; m < 64; m <<= 1) {
                s1 += __shfl_xor(s1, m, 64);
                s2 += __shfl_xor(s2, m, 64);
            }
            if (lane == 0) { lnp[tw*2] = s1; lnp[tw*2 + 1] = s2; }
            st_rel(&tfA[tw], t);
            wait_ge(&tfA[0], t); wait_ge(&tfA[1], t);
            wait_ge(&tfA[2], t); wait_ge(&tfA[3], t);
            const float mean = (lnp[0]+lnp[2]+lnp[4]+lnp[6]) * (1.0f/256.0f);
            const float ms   = (lnp[1]+lnp[3]+lnp[5]+lnp[7]) * (1.0f/256.0f);
            const float var  = fmaxf(ms - mean*mean, 0.0f);
            const float rs   = rsqrtf(var + 1e-5f);
            float h1v = fast_tanh((av - mean)*rs*gr + betar);
            if (!ph) h1loc[tw][lane >> 1] = h1v;   // rows tw*32 .. tw*32+31
            __builtin_amdgcn_wave_barrier();
            // ---- mv2: K-split = own wave's rows (wave-local, no sync) ----
            float p0 = 0.f, p1 = 0.f, p2 = 0.f, p3 = 0.f;
            const float4* h4 = (const float4*)h1loc[tw];
            #pragma unroll
            for (int k4 = 0; k4 < 8; k4++) {
                float4 h = h4[k4];
                p0 += V1[k4*4+0]*h.x;
                p1 += V1[k4*4+1]*h.y;
                p2 += V1[k4*4+2]*h.z;
                p3 += V1[k4*4+3]*h.w;
            }
            float p = (p0 + p1) + (p2 + p3);
            if (tw != 0) {
                p2s[tw][lane] = p;
                st_rel(&tfB[tw], t);
            } else {
                wait_ge(&tfB[1], t); wait_ge(&tfB[2], t); wait_ge(&tfB[3], t);
                float h2v = fast_tanh(b2r + p + p2s[1][lane]
                                          + p2s[2][lane] + p2s[3][lane]);
                // mv3: lane (4j+pp) partial over chunk pp*16..+15
                const int pp = lane & 3;
                float accm = 0.f;
                #pragma unroll
                for (int k = 0; k < 16; k++)
                    accm += V2[5 + k] * __shfl(h2v, pp*16 + k, 64);
                accm += __shfl_xor(accm, 1, 64);
                accm += __shfl_xor(accm, 2, 64);
                if (pp == 0 && lane < 40) {
                    const int j = lane >> 2;      // 0..9
                    float val = b3r + accm;
                    const size_t row = (size_t)b*T_ + t;
                    if (j < 5) {
                        z_s[j] = val;
                        out_tm[row*5 + j] = val;
                    } else {
                        out_tlv[row*5 + (j - 5)] = fminf(10.0f, fmaxf(-10.0f, val));
                    }
                }
                st_rel(&ttag_s, t);               // publishes z + step done
            }
        }
    }
}

// ---------------------------------------------------------------------------
// Observation decoder: one wave per row; weights in static LDS (~60 KB);
// h1/h2 are staged once per row into a per-wave LDS strip and re-read as
// BROADCAST float4 loads (same address across lanes = conflict-free, one DS
// op per 4 values). Accumulators split 4-way to break the serial FMA chain.
// ---------------------------------------------------------------------------
#define DEC_BLOCKS 512

__global__ __launch_bounds__(512) void dec_kernel(
    const float* __restrict__ ow1,
    const float* __restrict__ ob1,
    const float* __restrict__ og,
    const float* __restrict__ obeta,
    const float* __restrict__ ow2,
    const float* __restrict__ ob2,
    const float* __restrict__ ow3,
    const float* __restrict__ ob3,
    const float* __restrict__ tmeans,
    float* __restrict__ out_om,
    float* __restrict__ out_olv)
{
    __shared__ float w1s[640];    // [j*5+k]
    __shared__ float b1s[128], gs[128], bes[128];
    __shared__ float w2s[8192];   // [k*64+j] transposed
    __shared__ float b2s[64];
    __shared__ float w3s[4096];   // [k*64+j] transposed
    __shared__ float b3s[64];
    __shared__ __align__(16) float h1s[8][128];   // per-wave h1 strip
    __shared__ __align__(16) float h2s[8][64];    // per-wave h2 strip

    const int tid = threadIdx.x;
    for (int idx = tid; idx < 640; idx += 512) w1s[idx] = ow1[idx];
    for (int idx = tid; idx < 128; idx += 512) {
        b1s[idx] = ob1[idx]; gs[idx] = og[idx]; bes[idx] = obeta[idx];
    }
    for (int idx = tid; idx < 8192; idx += 512) {
        int k = idx >> 6, j = idx & 63;
        w2s[idx] = ow2[j*128 + k];
    }
    for (int idx = tid; idx < 4096; idx += 512) {
        int k = idx >> 6, j = idx & 63;
        w3s[idx] = ow3[j*64 + k];
    }
    for (int idx = tid; idx < 64; idx += 512) { b2s[idx] = ob2[idx]; b3s[idx] = ob3[idx]; }
    __syncthreads();

    const int lane   = tid & 63;
    const int wv     = tid >> 6;
    const int gwave  = (blockIdx.x * 512 + tid) >> 6;
    const int nwaves = DEC_BLOCKS * 8;
    const int j0 = lane, j1 = lane + 64;

    for (int row = gwave; row < B_*T_; row += nwaves) {
        const float z0v = tmeans[(size_t)row*5 + 0];
        const float z1v = tmeans[(size_t)row*5 + 1];
        const float z2v = tmeans[(size_t)row*5 + 2];
        const float z3v = tmeans[(size_t)row*5 + 3];
        const float z4v = tmeans[(size_t)row*5 + 4];

        // layer 1 (5 -> 128): lane holds outputs j0 and j1
        float a = b1s[j0] + w1s[j0*5+0]*z0v + w1s[j0*5+1]*z1v + w1s[j0*5+2]*z2v
                + w1s[j0*5+3]*z3v + w1s[j0*5+4]*z4v;
        float bb = b1s[j1] + w1s[j1*5+0]*z0v + w1s[j1*5+1]*z1v + w1s[j1*5+2]*z2v
                 + w1s[j1*5+3]*z3v + w1s[j1*5+4]*z4v;
        float s1 = a + bb, s2 = a*a + bb*bb;
        #pragma unroll
        for (int m = 1; m < 64; m <<= 1) {
            s1 += __shfl_xor(s1, m, 64);
            s2 += __shfl_xor(s2, m, 64);
        }
        const float mean = s1 * (1.0f/128.0f);
        const float var  = fmaxf(s2 * (1.0f/128.0f) - mean*mean, 0.0f);
        const float rs   = rsqrtf(var + 1e-5f);
        const float h1a  = fast_tanh((a  - mean)*rs*gs[j0] + bes[j0]);
        const float h1b  = fast_tanh((bb - mean)*rs*gs[j1] + bes[j1]);

        // stage h1 into the wave's private LDS strip (wave-synchronous)
        h1s[wv][lane]      = h1a;
        h1s[wv][64 + lane] = h1b;
        __builtin_amdgcn_wave_barrier();

        // layer 2 (128 -> 64): lane computes output j = lane.
        float acc2a = b2s[lane], acc2b = 0.f, acc2c = 0.f, acc2d = 0.f;
        const float4* h14 = (const float4*)(h1s[wv]);
        #pragma unroll
        for (int k4 = 0; k4 < 32; k4++) {
            float4 h = h14[k4];
            acc2a += h.x * w2s[(k4*4+0)*64 + lane];
            acc2b += h.y * w2s[(k4*4+1)*64 + lane];
            acc2c += h.z * w2s[(k4*4+2)*64 + lane];
            acc2d += h.w * w2s[(k4*4+3)*64 + lane];
        }
        const float h2v = fast_tanh(acc2a + acc2b + acc2c + acc2d);

        h2s[wv][lane] = h2v;
        __builtin_amdgcn_wave_barrier();

        // layer 3 (64 -> 64): lane computes output j = lane
        float acc3a = b3s[lane], acc3b = 0.f, acc3c = 0.f, acc3d = 0.f;
        const float4* h24 = (const float4*)(h2s[wv]);
        #pragma unroll
        for (int k4 = 0; k4 < 16; k4++) {
            float4 h = h24[k4];
            acc3a += h.x * w3s[(k4*4+0)*64 + lane];
            acc3b += h.y * w3s[(k4*4+1)*64 + lane];
            acc3c += h.z * w3s[(k4*4+2)*64 + lane];
            acc3d += h.w * w3s[(k4*4+3)*64 + lane];
        }
        const float acc3 = acc3a + acc3b + acc3c + acc3d;

        if (lane < 32) {
            out_om[(size_t)row*32 + lane] = acc3;
        } else {
            out_olv[(size_t)row*32 + (lane - 32)] = fminf(10.0f, fmaxf(-10.0f, acc3));
        }
    }
}

extern "C" void kernel_launch(void* const* d_in, const int* in_sizes, int n_in,
                              void* d_out, int out_size, void* d_ws, size_t ws_size,
                              hipStream_t stream) {
    const float* obs  = (const float*)d_in[0];
    const float* Wih  = (const float*)d_in[1];
    const float* Whh  = (const float*)d_in[2];
    const float* bih  = (const float*)d_in[3];
    const float* bhh  = (const float*)d_in[4];
    const float* tw1  = (const float*)d_in[5];
    const float* tb1  = (const float*)d_in[6];
    const float* tg   = (const float*)d_in[7];
    const float* tbe  = (const float*)d_in[8];
    const float* tw2  = (const float*)d_in[9];
    const float* tb2  = (const float*)d_in[10];
    const float* tw3  = (const float*)d_in[11];
    const float* tb3  = (const float*)d_in[12];
    const float* ow1  = (const float*)d_in[13];
    const float* ob1  = (const float*)d_in[14];
    const float* og   = (const float*)d_in[15];
    const float* obe  = (const float*)d_in[16];
    const float* ow2  = (const float*)d_in[17];
    const float* ob2  = (const float*)d_in[18];
    const float* ow3  = (const float*)d_in[19];
    const float* ob3  = (const float*)d_in[20];
    const float* z0m  = (const float*)d_in[21];
    const float* z0lv = (const float*)d_in[22];

    float* out0 = (float*)d_out;                   // obs_means   (B,T,32)
    float* out1 = out0 + (size_t)B_*T_*32;         // obs_logvars (B,T,32)
    float* out2 = out1 + (size_t)B_*T_*32;         // trans_means (B,T,5)
    float* out3 = out2 + (size_t)B_*T_*5;          // trans_logvars

    scan_kernel<<<B_, 512, 0, stream>>>(obs, Wih, Whh, bih, bhh,
                                        tw1, tb1, tg, tbe, tw2, tb2, tw3, tb3,
                                        z0m, z0lv, out2, out3);

    dec_kernel<<<DEC_BLOCKS, 512, 0, stream>>>(
        ow1, ob1, og, obe, ow2, ob2, ow3, ob3, out2, out0, out1);
}